// Round 13
// baseline (900.169 us; speedup 1.0000x reference)
//
#include <hip/hip_runtime.h>
#include <hip/hip_bf16.h>

// ---------------------------------------------------------------------------
// Problem constants (reference: B,N,T,P,H = 256,101,128,4,16)
// ---------------------------------------------------------------------------
constexpr int B = 256;
constexpr int N = 101;
constexpr int T = 128;

typedef float vf2 __attribute__((ext_vector_type(2)));
typedef short s8v __attribute__((ext_vector_type(8)));    // 8 bf16 (4 VGPRs)
typedef unsigned short u8v __attribute__((ext_vector_type(8)));
typedef unsigned short u4s __attribute__((ext_vector_type(4)));
typedef unsigned int u32x4 __attribute__((ext_vector_type(4)));
typedef float f4v __attribute__((ext_vector_type(4)));    // MFMA accum

__device__ __forceinline__ float frcp(float x) { return __builtin_amdgcn_rcpf(x); }
__device__ __forceinline__ float sigmoidf_(float x) { return frcp(1.f + __expf(-x)); }
__device__ __forceinline__ float tanhf_(float x) { return 2.f * frcp(1.f + __expf(-2.f * x)) - 1.f; }

// fp32 -> bf16 bits, round-nearest-even
__device__ __forceinline__ unsigned short f2bf(float x) {
  unsigned int u = __float_as_uint(x);
  u = (u + 0x7FFFu + ((u >> 16) & 1u)) >> 16;
  return (unsigned short)u;
}
// bf16 bits -> fp32
__device__ __forceinline__ float bf2f(unsigned short u) {
  return __uint_as_float((unsigned int)u << 16);
}
__device__ __forceinline__ unsigned pack2(float a, float b) {
  return (unsigned)f2bf(a) | ((unsigned)f2bf(b) << 16);
}

// XCD-aware n-swizzle. Bijection on [0,101). n and n+1 map to block indices
// 8 apart -> same XCD -> the ccm n±5 gather stays XCD-local.
__device__ __forceinline__ int swz_n(int L) {
  int q = L & 7, r = L >> 3;
  return q * 13 - (q > 5 ? (q - 5) : 0) + r;
}

// ---------------------------------------------------------------------------
// K1: LSTM via MFMA, shuffle-free recurrence (R12, measured ~116 us).
// R13: explicit one-step Xs prefetch pulls the ~120-cyc LDS read latency
// out of the 128-step serial chain. Bit-identical values.
// ---------------------------------------------------------------------------
__global__ __launch_bounds__(64) void lstm_kernel(
    const float* __restrict__ x, const float* __restrict__ pw,
    const float* __restrict__ pb, const float* __restrict__ w_ih,
    const float* __restrict__ w_hh, const float* __restrict__ b_ih,
    const float* __restrict__ b_hh, float* __restrict__ h_out) {
  __shared__ __align__(16) unsigned int Xs[T][16][2];  // 16 KB
  const int l = threadIdx.x;
  const int s = l & 15;       // seq within wave (B col); also A-row index
  const int q = l >> 4;       // k-group / D-row group
  const int row0 = blockIdx.x * 16;

  // ---- A fragments (one-time): gate j = m*16 + s, k = q*8+j2 ----
  // k-layout: j2<4 -> W_hh[j][q*4+j2] (lane-local h); j2>=4 -> q==0 ? Wf : 0
  s8v Afr[4];
#pragma unroll
  for (int m = 0; m < 4; m++) {
    const int j = m * 16 + s;
    float wfm[4];
#pragma unroll
    for (int p = 0; p < 4; p++) {
      float v = 0.f;
#pragma unroll
      for (int c = 0; c < 4; c++) v += w_ih[j * 4 + c] * pw[c * 4 + p];
      wfm[p] = v;
    }
    u8v av;
#pragma unroll
    for (int j2 = 0; j2 < 8; j2++) {
      float val;
      if (j2 < 4) val = w_hh[j * 16 + (q * 4 + j2)];
      else val = (q == 0) ? wfm[j2 - 4] : 0.f;
      av[j2] = f2bf(val);
    }
    Afr[m] = *(s8v*)&av;
  }
  // ---- bias (fp32, added post-MFMA): gate jb = m*16 + q*4 + r ----
  float bi[4][4];
#pragma unroll
  for (int m = 0; m < 4; m++) {
#pragma unroll
    for (int r = 0; r < 4; r++) {
      const int jb = m * 16 + q * 4 + r;
      float bp = b_ih[jb] + b_hh[jb];
#pragma unroll
      for (int c = 0; c < 4; c++) bp += w_ih[jb * 4 + c] * pb[c];
      bi[m][r] = bp;
    }
  }

  // ---- stage x -> LDS (one time; lane covers seq s at t = q + 4i) ----
  const float4* xp0 = (const float4*)x + (size_t)row0 * T;
#pragma unroll 8
  for (int i = 0; i < 32; i++) {
    const int t = q + i * 4;
    float4 v = xp0[(size_t)s * T + t];
    Xs[t][s][0] = pack2(v.x, v.y);
    Xs[t][s][1] = pack2(v.z, v.w);
  }
  __syncthreads();  // 1-wave block: compiles to waitcnt (free)

  float c0 = 0.f, c1 = 0.f, c2 = 0.f, c3 = 0.f;
  float h0 = 0.f, h1 = 0.f, h2 = 0.f, h3 = 0.f;
  unsigned X0c = Xs[0][s][0], X1c = Xs[0][s][1];

#pragma unroll 1
  for (int t = 0; t < T; t++) {
    // prefetch next step's x words (off the critical path)
    const int tn = (t + 1 < T) ? t + 1 : t;
    unsigned X0n = Xs[tn][s][0];
    unsigned X1n = Xs[tn][s][1];

    // ---- build B fragment: all lane-local ----
    unsigned b0 = pack2(h0, h1);
    unsigned b1 = pack2(h2, h3);
    unsigned b2 = (q == 0) ? X0c : 0u;
    unsigned b3 = (q == 0) ? X1c : 0u;
    u32x4 bu = {b0, b1, b2, b3};
    s8v Bfr = *(s8v*)&bu;

    // ---- 4 MFMAs: gate pre-activations ----
    f4v d0 = __builtin_amdgcn_mfma_f32_16x16x32_bf16(Afr[0], Bfr, (f4v)0.f, 0, 0, 0);
    f4v d1 = __builtin_amdgcn_mfma_f32_16x16x32_bf16(Afr[1], Bfr, (f4v)0.f, 0, 0, 0);
    f4v d2 = __builtin_amdgcn_mfma_f32_16x16x32_bf16(Afr[2], Bfr, (f4v)0.f, 0, 0, 0);
    f4v d3 = __builtin_amdgcn_mfma_f32_16x16x32_bf16(Afr[3], Bfr, (f4v)0.f, 0, 0, 0);

    // ---- lane-local c/h update (fp32) ----
    float iv, fv, gv, ov;
    iv = sigmoidf_(d0[0] + bi[0][0]); fv = sigmoidf_(d1[0] + bi[1][0]);
    gv = tanhf_(d2[0] + bi[2][0]);    ov = sigmoidf_(d3[0] + bi[3][0]);
    c0 = fv * c0 + iv * gv;           h0 = ov * tanhf_(c0);
    iv = sigmoidf_(d0[1] + bi[0][1]); fv = sigmoidf_(d1[1] + bi[1][1]);
    gv = tanhf_(d2[1] + bi[2][1]);    ov = sigmoidf_(d3[1] + bi[3][1]);
    c1 = fv * c1 + iv * gv;           h1 = ov * tanhf_(c1);
    iv = sigmoidf_(d0[2] + bi[0][2]); fv = sigmoidf_(d1[2] + bi[1][2]);
    gv = tanhf_(d2[2] + bi[2][2]);    ov = sigmoidf_(d3[2] + bi[3][2]);
    c2 = fv * c2 + iv * gv;           h2 = ov * tanhf_(c2);
    iv = sigmoidf_(d0[3] + bi[0][3]); fv = sigmoidf_(d1[3] + bi[1][3]);
    gv = tanhf_(d2[3] + bi[2][3]);    ov = sigmoidf_(d3[3] + bi[3][3]);
    c3 = fv * c3 + iv * gv;           h3 = ov * tanhf_(c3);

    X0c = X0n;
    X1c = X1n;
  }
  float* op = &h_out[(size_t)(row0 + s) * 16 + q * 4];
  op[0] = h0; op[1] = h1; op[2] = h2; op[3] = h3;
}

// ---------------------------------------------------------------------------
// Prep: pack conv weights into MFMA A-fragment order (bf16).
// Sets 0..14: cc convs. Sets 15..21: d1/d2 of stages 2/3 (K=jt*CIeff+ci,
// zero-padded past K=3*CIeff so the B pad region needs no masking):
//   15: s2 d1 (CIw=8)   16,17: s2 d2   18,19: s3 d1   20,21: s3 d2
// ---------------------------------------------------------------------------
__global__ void prep_kernel(const float* __restrict__ t1c,
                            const float* __restrict__ t2c,
                            const float* __restrict__ t3c,
                            const float* __restrict__ t2d1,
                            const float* __restrict__ t2d2,
                            const float* __restrict__ t3d1,
                            const float* __restrict__ t3d2,
                            unsigned short* __restrict__ apk) {
  const int L = threadIdx.x;  // 64 threads
  const int co = L & 15, q = L >> 4;
#pragma unroll 1
  for (int set = 0; set < 15; set++) {
    int s, p;
    if (set < 3) { s = 0; p = set; }
    else if (set < 9) { s = 1; p = set - 3; }
    else { s = 2; p = set - 9; }
    u8v f;
#pragma unroll
    for (int j = 0; j < 8; j++) {
      float val = 0.f;
      if (s == 0) {
        int dn = p * 4 + q, ci = j;
        if (co < 8 && dn < 11) val = t1c[(co * 8 + ci) * 11 + dn];
      } else {
        int dn = p * 2 + (q >> 1), ci = (q & 1) * 8 + j;
        const float* w = (s == 1) ? t2c : t3c;
        if (dn < 11) val = w[(co * 16 + ci) * 11 + dn];
      }
      f[j] = f2bf(val);
    }
    *(u8v*)&apk[(set * 64 + L) * 8] = f;
  }
#pragma unroll 1
  for (int ds = 0; ds < 7; ds++) {
    const float* w; int CIw, CIeff, kk;
    switch (ds) {
      case 0: w = t2d1; CIw = 8;  CIeff = 8;  kk = 0; break;
      case 1: w = t2d2; CIw = 16; CIeff = 16; kk = 0; break;
      case 2: w = t2d2; CIw = 16; CIeff = 16; kk = 1; break;
      case 3: w = t3d1; CIw = 16; CIeff = 16; kk = 0; break;
      case 4: w = t3d1; CIw = 16; CIeff = 16; kk = 1; break;
      case 5: w = t3d2; CIw = 16; CIeff = 16; kk = 0; break;
      default: w = t3d2; CIw = 16; CIeff = 16; kk = 1; break;
    }
    u8v f;
#pragma unroll
    for (int j = 0; j < 8; j++) {
      int kg = kk * 32 + q * 8 + j;
      int ci = kg % CIeff, jt = kg / CIeff;
      float val = (jt < 3) ? w[(co * CIw + ci) * 3 + jt] : 0.f;
      f[j] = f2bf(val);
    }
    *(u8v*)&apk[((15 + ds) * 64 + L) * 8] = f;
  }
}

// ---------------------------------------------------------------------------
// K2 (stage 1 only): fused d1+d2, proj folded, fp32 x input, bf16
// channel-interleaved output [by][n][t][8].
// ---------------------------------------------------------------------------
__global__ __launch_bounds__(128) void d12a_kernel(
    const float* __restrict__ xin,
    const float* __restrict__ pw, const float* __restrict__ pb,
    const float* __restrict__ w1,  // [8][4][3]
    const float* __restrict__ w2,  // [8][8][3]
    unsigned short* __restrict__ out, int b0) {
  constexpr int CI = 4, CO = 8, DIL = 1;
  const int t = threadIdx.x;
  const int n = swz_n(blockIdx.x), by = blockIdx.y;
  const int b = b0 + by;

  float r1[3][CO];
#pragma unroll
  for (int u = 0; u < 3; u++)
#pragma unroll
    for (int co = 0; co < CO; co++) r1[u][co] = 0.f;

  const float4* xp = (const float4*)xin + ((size_t)b * N + n) * T;
  float px[5][4];
#pragma unroll
  for (int v = 0; v < 5; v++) {
    int idx = t - v * DIL;
    float4 xr = xp[idx < 0 ? 0 : idx];
    bool ok = idx >= 0;
    px[v][0] = ok ? pb[0] + pw[0] * xr.x + pw[1] * xr.y + pw[2] * xr.z + pw[3] * xr.w : 0.f;
    px[v][1] = ok ? pb[1] + pw[4] * xr.x + pw[5] * xr.y + pw[6] * xr.z + pw[7] * xr.w : 0.f;
    px[v][2] = ok ? pb[2] + pw[8] * xr.x + pw[9] * xr.y + pw[10] * xr.z + pw[11] * xr.w : 0.f;
    px[v][3] = ok ? pb[3] + pw[12] * xr.x + pw[13] * xr.y + pw[14] * xr.z + pw[15] * xr.w : 0.f;
  }
#pragma unroll
  for (int ci = 0; ci < CI; ci++) {
#pragma unroll
    for (int j = 0; j < 3; j++) {
#pragma unroll
      for (int co = 0; co < CO; co++) {
        float w = w1[(co * CI + ci) * 3 + j];
#pragma unroll
        for (int u = 0; u < 3; u++) r1[u][co] += w * px[u + 2 - j][ci];
      }
    }
  }
#pragma unroll
  for (int u = 0; u < 3; u++)
#pragma unroll
    for (int co = 0; co < CO; co++) r1[u][co] = fmaxf(r1[u][co], 0.f);

  float acc[CO];
#pragma unroll
  for (int co = 0; co < CO; co++) acc[co] = 0.f;
#pragma unroll
  for (int cm = 0; cm < CO; cm++) {
#pragma unroll
    for (int j = 0; j < 3; j++) {
#pragma unroll
      for (int co = 0; co < CO; co++)
        acc[co] += w2[(co * CO + cm) * 3 + j] * r1[2 - j][cm];
    }
  }
  unsigned short* op = &out[(((size_t)by * N + n) * T + t) * CO];
  u8v a;
#pragma unroll
  for (int j = 0; j < 8; j++) a[j] = f2bf(fmaxf(acc[j], 0.f));
  *(u8v*)&op[0] = a;
}

// ---------------------------------------------------------------------------
// cd2: FUSED ccm (cross-stock 11x1 via MFMA, +residual) -> H, then the next
// stage's d1+d2 -> z. R10 structure (measured-best chain): 128-thread blocks
// = two independent (n,by) jobs (wave wv handles by = blockIdx.y*2+wv).
//   C==8 : ccm t1 (NMF=3, x-proj residual), d12 stage2 (CI=8,  DIL=2)
//   C==16: ccm t2 (NMF=6, rw@H1 residual),  d12 stage3 (CI=16, DIL=4)
// ---------------------------------------------------------------------------
template <int C, int DIL>
__global__ __launch_bounds__(128) void cd2_kernel(
    const unsigned short* __restrict__ zin,   // [Bc][N][T][C] bf16
    const unsigned short* __restrict__ apkc,  // ccm A-frags [NMF][64][8]
    const unsigned short* __restrict__ apkd,  // d12 A-frags (d1 then d2)
    const void* __restrict__ resin,           // C==8: fp32 x; C==16: bf16 H1
    const float* __restrict__ rw,
    const float* __restrict__ pw, const float* __restrict__ pb,
    unsigned short* __restrict__ hout,        // [Bc][N][T][C] bf16
    unsigned short* __restrict__ zout,        // [Bc][N][T][16] bf16
    int b0) {
  constexpr int NMF = (C == 8) ? 3 : 6;
  constexpr int HALO = 8;
  __shared__ __align__(16) unsigned short Hs[2][HALO + T][C];
  __shared__ __align__(16) unsigned short Rs[2][HALO + T][16];
  const int wv = threadIdx.x >> 6;  // job within block
  const int wl = threadIdx.x & 63;  // lane within wave
  const int tcol = wl & 15, q = wl >> 4;
  const int n = swz_n(blockIdx.x);
  const int by = blockIdx.y * 2 + wv;
  const int b = b0 + by;

  // zero own halos (causal zero-pad; tap reach 2*DIL <= 8)
  if (wl < 16) {
    *(u8v*)&Rs[wv][wl >> 1][(wl & 1) * 8] = (u8v)0;
    if constexpr (C == 8) {
      if (wl < 8) *(u8v*)&Hs[wv][wl][0] = (u8v)0;
    } else {
      *(u8v*)&Hs[wv][wl >> 1][(wl & 1) * 8] = (u8v)0;
    }
  }

  // A fragments (64-lane patterns -> wl)
  s8v ac[NMF];
#pragma unroll
  for (int p = 0; p < NMF; p++) ac[p] = *(const s8v*)&apkc[(p * 64 + wl) * 8];
  constexpr int ND1 = (C == 8) ? 1 : 2;
  s8v a1_0 = *(const s8v*)&apkd[(0 * 64 + wl) * 8];
  s8v a1_1 = a1_0;
  if constexpr (C == 16) a1_1 = *(const s8v*)&apkd[(1 * 64 + wl) * 8];
  s8v a2_0 = *(const s8v*)&apkd[((ND1 + 0) * 64 + wl) * 8];
  s8v a2_1 = *(const s8v*)&apkd[((ND1 + 1) * 64 + wl) * 8];

  // ---- phase 1: ccm + residual -> H (global + LDS) ----
#pragma unroll 1
  for (int tt = 0; tt < 8; tt++) {
    const int t = tt * 16 + tcol;
    f4v d = (f4v)0.f;
#pragma unroll
    for (int p = 0; p < NMF; p++) {
      int dn = (C == 8) ? (p * 4 + q) : (p * 2 + (q >> 1));
      int row = n + dn - 5;
      bool ok = (unsigned)row < (unsigned)N;
      int rowc = ok ? row : 0;
      const unsigned short* bp =
          &zin[(((size_t)by * N + rowc) * T + t) * C + ((C == 16) ? (q & 1) * 8 : 0)];
      s8v bfrag = *(const s8v*)bp;
      if (!ok) bfrag = (s8v){0, 0, 0, 0, 0, 0, 0, 0};
      d = __builtin_amdgcn_mfma_f32_16x16x32_bf16(ac[p], bfrag, d, 0, 0, 0);
    }
    if constexpr (C == 8) {
      if (q < 2) {
        float4 xr = ((const float4*)resin)[((size_t)b * N + n) * T + t];
        float xv[4];
#pragma unroll
        for (int j = 0; j < 4; j++)
          xv[j] = pb[j] + pw[j * 4 + 0] * xr.x + pw[j * 4 + 1] * xr.y +
                  pw[j * 4 + 2] * xr.z + pw[j * 4 + 3] * xr.w;
        u4s hb16;
#pragma unroll
        for (int r = 0; r < 4; r++) {
          int co = q * 4 + r;
          float rv = rw[co * 4 + 0] * xv[0] + rw[co * 4 + 1] * xv[1] +
                     rw[co * 4 + 2] * xv[2] + rw[co * 4 + 3] * xv[3];
          hb16[r] = f2bf(fmaxf(rv + fmaxf(d[r], 0.f), 0.f));
        }
        *(u4s*)&hout[(((size_t)by * N + n) * T + t) * 8 + q * 4] = hb16;
        *(u4s*)&Hs[wv][HALO + t][q * 4] = hb16;
      }
    } else {
      const unsigned short* hp =
          (const unsigned short*)resin + (((size_t)by * N + n) * T + t) * 8;
      u8v hb = *(const u8v*)hp;  // H1: 8 channels
      float hv[8];
#pragma unroll
      for (int ci = 0; ci < 8; ci++) hv[ci] = bf2f(hb[ci]);
      u4s hb16;
#pragma unroll
      for (int r = 0; r < 4; r++) {
        int co = q * 4 + r;
        float rv = 0.f;
#pragma unroll
        for (int ci = 0; ci < 8; ci++) rv += rw[co * 8 + ci] * hv[ci];
        hb16[r] = f2bf(fmaxf(rv + fmaxf(d[r], 0.f), 0.f));
      }
      *(u4s*)&hout[(((size_t)by * N + n) * T + t) * 16 + q * 4] = hb16;
      *(u4s*)&Hs[wv][HALO + t][q * 4] = hb16;
    }
  }
  __syncthreads();

  // ---- phase 2: d1 from Hs -> Rs ----
#pragma unroll 2
  for (int tt = 0; tt < 8; tt++) {
    const int t = tt * 16 + tcol;
    f4v acc = (f4v)0.f;
    if constexpr (C == 8) {
      const int jt = (q < 3) ? q : 2;  // q==3 is A-zero pad
      s8v bf = *(const s8v*)&Hs[wv][HALO + t - DIL * jt][0];
      acc = __builtin_amdgcn_mfma_f32_16x16x32_bf16(a1_0, bf, acc, 0, 0, 0);
    } else {
      {
        const int jt = q >> 1, ci0 = (q & 1) * 8;
        s8v bf = *(const s8v*)&Hs[wv][HALO + t - DIL * jt][ci0];
        acc = __builtin_amdgcn_mfma_f32_16x16x32_bf16(a1_0, bf, acc, 0, 0, 0);
      }
      {
        const int ci0 = (q & 1) * 8;  // jt=2 for q<2; A-zero pad otherwise
        s8v bf = *(const s8v*)&Hs[wv][HALO + t - DIL * 2][ci0];
        acc = __builtin_amdgcn_mfma_f32_16x16x32_bf16(a1_1, bf, acc, 0, 0, 0);
      }
    }
    u4s rb;
#pragma unroll
    for (int r = 0; r < 4; r++) rb[r] = f2bf(fmaxf(acc[r], 0.f));
    *(u4s*)&Rs[wv][HALO + t][q * 4] = rb;
  }
  __syncthreads();

  // ---- phase 3: d2 from Rs -> zout ----
  unsigned short* opb = &zout[((size_t)by * N + n) * T * 16];
#pragma unroll 2
  for (int tt = 0; tt < 8; tt++) {
    const int t = tt * 16 + tcol;
    f4v acc = (f4v)0.f;
    {
      const int jt = q >> 1, ci0 = (q & 1) * 8;
      s8v bf = *(const s8v*)&Rs[wv][HALO + t - DIL * jt][ci0];
      acc = __builtin_amdgcn_mfma_f32_16x16x32_bf16(a2_0, bf, acc, 0, 0, 0);
    }
    {
      const int ci0 = (q & 1) * 8;
      s8v bf = *(const s8v*)&Rs[wv][HALO + t - DIL * 2][ci0];
      acc = __builtin_amdgcn_mfma_f32_16x16x32_bf16(a2_1, bf, acc, 0, 0, 0);
    }
    u4s ob;
#pragma unroll
    for (int r = 0; r < 4; r++) ob[r] = f2bf(fmaxf(acc[r], 0.f));
    *(u4s*)&opb[(size_t)t * 16 + q * 4] = ob;
  }
}

// ---------------------------------------------------------------------------
// cy: FUSED ccm t3 (identity residual) -> Y (fp32, LDS only) -> conv4 -> h4.
// R10 structure: 128-thread blocks = two independent (n,by) jobs.
// ---------------------------------------------------------------------------
__global__ __launch_bounds__(128) void cy_kernel(
    const unsigned short* __restrict__ zin,   // Zb2b [Bc][N][T][16] bf16
    const unsigned short* __restrict__ apkc,  // sets 9..14
    const unsigned short* __restrict__ resin, // H2 [Bc][N][T][16] bf16
    const float* __restrict__ w4,             // [16][16][T]
    float* __restrict__ h4,                   // [B][16][N]
    int b0) {
  __shared__ __align__(16) float Ys[2][16][T + 2];
  const int wv = threadIdx.x >> 6;
  const int wl = threadIdx.x & 63;
  const int tcol = wl & 15, q = wl >> 4;
  const int n = swz_n(blockIdx.x);
  const int by = blockIdx.y * 2 + wv;
  const int b = b0 + by;

  s8v ac[6];
#pragma unroll
  for (int p = 0; p < 6; p++) ac[p] = *(const s8v*)&apkc[(p * 64 + wl) * 8];

  // ---- phase 1: ccm t3 -> Ys (fp32 LDS) ----
#pragma unroll 1
  for (int tt = 0; tt < 8; tt++) {
    const int t = tt * 16 + tcol;
    f4v d = (f4v)0.f;
#pragma unroll
    for (int p = 0; p < 6; p++) {
      int dn = p * 2 + (q >> 1);
      int row = n + dn - 5;
      bool ok = (unsigned)row < (unsigned)N;
      int rowc = ok ? row : 0;
      const unsigned short* bp =
          &zin[(((size_t)by * N + rowc) * T + t) * 16 + (q & 1) * 8];
      s8v bfrag = *(const s8v*)bp;
      if (!ok) bfrag = (s8v){0, 0, 0, 0, 0, 0, 0, 0};
      d = __builtin_amdgcn_mfma_f32_16x16x32_bf16(ac[p], bfrag, d, 0, 0, 0);
    }
    const unsigned short* hp = resin + (((size_t)by * N + n) * T + t) * 16 + q * 4;
    u4s hb = *(const u4s*)hp;
#pragma unroll
    for (int r = 0; r < 4; r++)
      Ys[wv][q * 4 + r][t] = fmaxf(bf2f(hb[r]) + fmaxf(d[r], 0.f), 0.f);
  }
  __syncthreads();

  // ---- phase 2: conv4 (full-T dot per output channel, wave reduce) ----
  const int t0 = wl * 2;
  vf2 y[16];
#pragma unroll
  for (int ci = 0; ci < 16; ci++) y[ci] = *(const vf2*)&Ys[wv][ci][t0];

#pragma unroll 1
  for (int o = 0; o < 16; o++) {
    vf2 s = (vf2)0.f;
#pragma unroll
    for (int ci = 0; ci < 16; ci++) {
      vf2 w = *(const vf2*)&w4[(size_t)(o * 16 + ci) * T + t0];
      s += w * y[ci];
    }
    float sum = s.x + s.y;
    sum += __shfl_down(sum, 32);
    sum += __shfl_down(sum, 16);
    sum += __shfl_down(sum, 8);
    sum += __shfl_down(sum, 4);
    sum += __shfl_down(sum, 2);
    sum += __shfl_down(sum, 1);
    if (wl == 0) h4[((size_t)b * 16 + o) * N + n] = fmaxf(sum, 0.f);
  }
}

// ---------------------------------------------------------------------------
// K8: logits (torch reshape scramble) + softmax over N
// ---------------------------------------------------------------------------
__global__ __launch_bounds__(128) void final_kernel(
    const float* __restrict__ hl, const float* __restrict__ h4,
    const float* __restrict__ ow, const float* __restrict__ ob,
    float* __restrict__ out) {
  __shared__ float red[128];
  int b = blockIdx.x, n = threadIdx.x;
  bool valid = n < N;
  float lv = 0.f;
  if (valid) {
    int idx = b * N + n;
    int sb = idx & (B - 1);
    int sn = idx >> 8;
    const float* h = &hl[((size_t)sb * N + sn) * 16];
    float a = ob[0];
#pragma unroll
    for (int k = 0; k < 16; k++) a += h[k] * ow[k];
#pragma unroll
    for (int c = 0; c < 16; c++) a += h4[((size_t)b * 16 + c) * N + n] * ow[16 + c];
    lv = a;
  }
  red[n] = valid ? lv : -1e30f;
  __syncthreads();
  for (int off = 64; off > 0; off >>= 1) {
    if (n < off) red[n] = fmaxf(red[n], red[n + off]);
    __syncthreads();
  }
  float m = red[0];
  __syncthreads();
  float e = valid ? __expf(lv - m) : 0.f;
  red[n] = e;
  __syncthreads();
  for (int off = 64; off > 0; off >>= 1) {
    if (n < off) red[n] += red[n + off];
    __syncthreads();
  }
  float s = red[0];
  if (valid) out[(size_t)b * N + n] = e / s;
}

// ---------------------------------------------------------------------------
// Launch. Chunked over B. Buffers (all bf16 interleaved [Bc][N][T][C]):
// Zb1(8ch=4) + H1b(8ch=4) + Zb2a(16ch=8) + H2b(16ch=8) + Zb2b(16ch=8)
// = 32 NT-floats per b. R13: Bc CAPPED AT 32 so the per-dispatch z footprint
// (~13 MB aggregate, ~1.7 MB/XCD) stays L2-resident — the swz_n mapping keeps
// producer and consumer of each (n-neighborhood, by) on the SAME XCD, so all
// cross-kernel z/H traffic becomes L2 hits instead of L3/HBM-latency misses
// (the diagnosed chain bottleneck; FETCH was 73 MB/dispatch at large Bc).
// ---------------------------------------------------------------------------
extern "C" void kernel_launch(void* const* d_in, const int* in_sizes, int n_in,
                              void* d_out, int out_size, void* d_ws, size_t ws_size,
                              hipStream_t stream) {
  const float* x    = (const float*)d_in[0];
  const float* pw   = (const float*)d_in[1];
  const float* pb   = (const float*)d_in[2];
  const float* w_ih = (const float*)d_in[3];
  const float* w_hh = (const float*)d_in[4];
  const float* b_ih = (const float*)d_in[5];
  const float* b_hh = (const float*)d_in[6];
  const float* t1d1 = (const float*)d_in[7];
  const float* t1d2 = (const float*)d_in[8];
  const float* t1c  = (const float*)d_in[9];
  const float* t1r  = (const float*)d_in[10];
  const float* t2d1 = (const float*)d_in[11];
  const float* t2d2 = (const float*)d_in[12];
  const float* t2c  = (const float*)d_in[13];
  const float* t2r  = (const float*)d_in[14];
  const float* t3d1 = (const float*)d_in[15];
  const float* t3d2 = (const float*)d_in[16];
  const float* t3c  = (const float*)d_in[17];
  const float* w4   = (const float*)d_in[18];
  const float* ow   = (const float*)d_in[19];
  const float* ob   = (const float*)d_in[20];
  float* outp = (float*)d_out;

  const size_t NT = (size_t)N * T;            // 12928
  const size_t Bn16 = (size_t)B * N * 16;
  const size_t unit = 32 * NT;                // floats per chunked b
  const size_t fixed = 2 * Bn16 + 8192;       // hl + h4 + apk

  int Bc = 4;
  const int cands[4] = {32, 16, 8, 4};        // cap at 32 for L2 residency
  for (int i = 0; i < 4; i++) {
    if ((cands[i] * unit + fixed) * sizeof(float) <= ws_size) { Bc = cands[i]; break; }
  }

  float* ws = (float*)d_ws;
  float* hl = ws;                              // [B*N][16]
  float* h4 = hl + Bn16;                       // [B][16][N]
  unsigned short* apk = (unsigned short*)(h4 + Bn16);  // 22*512 ushorts
  float* p = h4 + Bn16 + 8192;
  unsigned short* Zb1  = (unsigned short*)p; p += (size_t)Bc * 4 * NT;
  unsigned short* H1b  = (unsigned short*)p; p += (size_t)Bc * 4 * NT;
  unsigned short* Zb2a = (unsigned short*)p; p += (size_t)Bc * 8 * NT;
  unsigned short* H2b  = (unsigned short*)p; p += (size_t)Bc * 8 * NT;
  unsigned short* Zb2b = (unsigned short*)p;

  prep_kernel<<<1, 64, 0, stream>>>(t1c, t2c, t3c, t2d1, t2d2, t3d1, t3d2, apk);
  lstm_kernel<<<(B * N) / 16, 64, 0, stream>>>(x, pw, pb, w_ih, w_hh, b_ih,
                                               b_hh, hl);

  dim3 g(N, Bc);
  dim3 g2(N, Bc / 2);
  for (int b0 = 0; b0 < B; b0 += Bc) {
    d12a_kernel<<<g, 128, 0, stream>>>(x, pw, pb, t1d1, t1d2, Zb1, b0);
    cd2_kernel<8, 2><<<g2, 128, 0, stream>>>(
        Zb1, apk + 0 * 512, apk + 15 * 512, x, t1r, pw, pb, H1b, Zb2a, b0);
    cd2_kernel<16, 4><<<g2, 128, 0, stream>>>(
        Zb2a, apk + 3 * 512, apk + 18 * 512, H1b, t2r, pw, pb, H2b, Zb2b, b0);
    cy_kernel<<<g2, 128, 0, stream>>>(Zb2b, apk + 9 * 512, H2b, w4, h4, b0);
  }

  final_kernel<<<B, 128, 0, stream>>>(hl, h4, ow, ob, outp);
}

// Round 14
// 725.699 us; speedup vs baseline: 1.2404x; 1.2404x over previous
//
#include <hip/hip_runtime.h>
#include <hip/hip_bf16.h>

// ---------------------------------------------------------------------------
// Problem constants (reference: B,N,T,P,H = 256,101,128,4,16)
// ---------------------------------------------------------------------------
constexpr int B = 256;
constexpr int N = 101;
constexpr int T = 128;

typedef float vf2 __attribute__((ext_vector_type(2)));
typedef short s8v __attribute__((ext_vector_type(8)));    // 8 bf16 (4 VGPRs)
typedef unsigned short u8v __attribute__((ext_vector_type(8)));
typedef unsigned short u4s __attribute__((ext_vector_type(4)));
typedef unsigned int u32x4 __attribute__((ext_vector_type(4)));
typedef float f4v __attribute__((ext_vector_type(4)));    // MFMA accum

__device__ __forceinline__ float frcp(float x) { return __builtin_amdgcn_rcpf(x); }
__device__ __forceinline__ float sigmoidf_(float x) { return frcp(1.f + __expf(-x)); }
__device__ __forceinline__ float tanhf_(float x) { return 2.f * frcp(1.f + __expf(-2.f * x)) - 1.f; }

// fp32 -> bf16 bits, round-nearest-even
__device__ __forceinline__ unsigned short f2bf(float x) {
  unsigned int u = __float_as_uint(x);
  u = (u + 0x7FFFu + ((u >> 16) & 1u)) >> 16;
  return (unsigned short)u;
}
// bf16 bits -> fp32
__device__ __forceinline__ float bf2f(unsigned short u) {
  return __uint_as_float((unsigned int)u << 16);
}
__device__ __forceinline__ unsigned pack2(float a, float b) {
  return (unsigned)f2bf(a) | ((unsigned)f2bf(b) << 16);
}

// XCD-aware n-swizzle. Bijection on [0,101). n and n+1 map to block indices
// 8 apart -> same XCD -> the ccm n±5 gather stays XCD-local.
__device__ __forceinline__ int swz_n(int L) {
  int q = L & 7, r = L >> 3;
  return q * 13 - (q > 5 ? (q - 5) : 0) + r;
}

// ---------------------------------------------------------------------------
// K1: LSTM via MFMA, shuffle-free recurrence (R12/R13, measured ~116 us).
// Explicit one-step Xs prefetch; bit-identical values.
// ---------------------------------------------------------------------------
__global__ __launch_bounds__(64) void lstm_kernel(
    const float* __restrict__ x, const float* __restrict__ pw,
    const float* __restrict__ pb, const float* __restrict__ w_ih,
    const float* __restrict__ w_hh, const float* __restrict__ b_ih,
    const float* __restrict__ b_hh, float* __restrict__ h_out) {
  __shared__ __align__(16) unsigned int Xs[T][16][2];  // 16 KB
  const int l = threadIdx.x;
  const int s = l & 15;       // seq within wave (B col); also A-row index
  const int q = l >> 4;       // k-group / D-row group
  const int row0 = blockIdx.x * 16;

  // ---- A fragments (one-time): gate j = m*16 + s, k = q*8+j2 ----
  // k-layout: j2<4 -> W_hh[j][q*4+j2] (lane-local h); j2>=4 -> q==0 ? Wf : 0
  s8v Afr[4];
#pragma unroll
  for (int m = 0; m < 4; m++) {
    const int j = m * 16 + s;
    float wfm[4];
#pragma unroll
    for (int p = 0; p < 4; p++) {
      float v = 0.f;
#pragma unroll
      for (int c = 0; c < 4; c++) v += w_ih[j * 4 + c] * pw[c * 4 + p];
      wfm[p] = v;
    }
    u8v av;
#pragma unroll
    for (int j2 = 0; j2 < 8; j2++) {
      float val;
      if (j2 < 4) val = w_hh[j * 16 + (q * 4 + j2)];
      else val = (q == 0) ? wfm[j2 - 4] : 0.f;
      av[j2] = f2bf(val);
    }
    Afr[m] = *(s8v*)&av;
  }
  // ---- bias (fp32, added post-MFMA): gate jb = m*16 + q*4 + r ----
  float bi[4][4];
#pragma unroll
  for (int m = 0; m < 4; m++) {
#pragma unroll
    for (int r = 0; r < 4; r++) {
      const int jb = m * 16 + q * 4 + r;
      float bp = b_ih[jb] + b_hh[jb];
#pragma unroll
      for (int c = 0; c < 4; c++) bp += w_ih[jb * 4 + c] * pb[c];
      bi[m][r] = bp;
    }
  }

  // ---- stage x -> LDS (one time; lane covers seq s at t = q + 4i) ----
  const float4* xp0 = (const float4*)x + (size_t)row0 * T;
#pragma unroll 8
  for (int i = 0; i < 32; i++) {
    const int t = q + i * 4;
    float4 v = xp0[(size_t)s * T + t];
    Xs[t][s][0] = pack2(v.x, v.y);
    Xs[t][s][1] = pack2(v.z, v.w);
  }
  __syncthreads();  // 1-wave block: compiles to waitcnt (free)

  float c0 = 0.f, c1 = 0.f, c2 = 0.f, c3 = 0.f;
  float h0 = 0.f, h1 = 0.f, h2 = 0.f, h3 = 0.f;
  unsigned X0c = Xs[0][s][0], X1c = Xs[0][s][1];

#pragma unroll 1
  for (int t = 0; t < T; t++) {
    // prefetch next step's x words (off the critical path)
    const int tn = (t + 1 < T) ? t + 1 : t;
    unsigned X0n = Xs[tn][s][0];
    unsigned X1n = Xs[tn][s][1];

    // ---- build B fragment: all lane-local ----
    unsigned b0 = pack2(h0, h1);
    unsigned b1 = pack2(h2, h3);
    unsigned b2 = (q == 0) ? X0c : 0u;
    unsigned b3 = (q == 0) ? X1c : 0u;
    u32x4 bu = {b0, b1, b2, b3};
    s8v Bfr = *(s8v*)&bu;

    // ---- 4 MFMAs: gate pre-activations ----
    f4v d0 = __builtin_amdgcn_mfma_f32_16x16x32_bf16(Afr[0], Bfr, (f4v)0.f, 0, 0, 0);
    f4v d1 = __builtin_amdgcn_mfma_f32_16x16x32_bf16(Afr[1], Bfr, (f4v)0.f, 0, 0, 0);
    f4v d2 = __builtin_amdgcn_mfma_f32_16x16x32_bf16(Afr[2], Bfr, (f4v)0.f, 0, 0, 0);
    f4v d3 = __builtin_amdgcn_mfma_f32_16x16x32_bf16(Afr[3], Bfr, (f4v)0.f, 0, 0, 0);

    // ---- lane-local c/h update (fp32) ----
    float iv, fv, gv, ov;
    iv = sigmoidf_(d0[0] + bi[0][0]); fv = sigmoidf_(d1[0] + bi[1][0]);
    gv = tanhf_(d2[0] + bi[2][0]);    ov = sigmoidf_(d3[0] + bi[3][0]);
    c0 = fv * c0 + iv * gv;           h0 = ov * tanhf_(c0);
    iv = sigmoidf_(d0[1] + bi[0][1]); fv = sigmoidf_(d1[1] + bi[1][1]);
    gv = tanhf_(d2[1] + bi[2][1]);    ov = sigmoidf_(d3[1] + bi[3][1]);
    c1 = fv * c1 + iv * gv;           h1 = ov * tanhf_(c1);
    iv = sigmoidf_(d0[2] + bi[0][2]); fv = sigmoidf_(d1[2] + bi[1][2]);
    gv = tanhf_(d2[2] + bi[2][2]);    ov = sigmoidf_(d3[2] + bi[3][2]);
    c2 = fv * c2 + iv * gv;           h2 = ov * tanhf_(c2);
    iv = sigmoidf_(d0[3] + bi[0][3]); fv = sigmoidf_(d1[3] + bi[1][3]);
    gv = tanhf_(d2[3] + bi[2][3]);    ov = sigmoidf_(d3[3] + bi[3][3]);
    c3 = fv * c3 + iv * gv;           h3 = ov * tanhf_(c3);

    X0c = X0n;
    X1c = X1n;
  }
  float* op = &h_out[(size_t)(row0 + s) * 16 + q * 4];
  op[0] = h0; op[1] = h1; op[2] = h2; op[3] = h3;
}

// ---------------------------------------------------------------------------
// Prep: pack conv weights into MFMA A-fragment order (bf16).
// Sets 0..14: cc convs. Sets 15..21: d1/d2 of stages 2/3 (K=jt*CIeff+ci,
// zero-padded past K=3*CIeff so the B pad region needs no masking):
//   15: s2 d1 (CIw=8)   16,17: s2 d2   18,19: s3 d1   20,21: s3 d2
// ---------------------------------------------------------------------------
__global__ void prep_kernel(const float* __restrict__ t1c,
                            const float* __restrict__ t2c,
                            const float* __restrict__ t3c,
                            const float* __restrict__ t2d1,
                            const float* __restrict__ t2d2,
                            const float* __restrict__ t3d1,
                            const float* __restrict__ t3d2,
                            unsigned short* __restrict__ apk) {
  const int L = threadIdx.x;  // 64 threads
  const int co = L & 15, q = L >> 4;
#pragma unroll 1
  for (int set = 0; set < 15; set++) {
    int s, p;
    if (set < 3) { s = 0; p = set; }
    else if (set < 9) { s = 1; p = set - 3; }
    else { s = 2; p = set - 9; }
    u8v f;
#pragma unroll
    for (int j = 0; j < 8; j++) {
      float val = 0.f;
      if (s == 0) {
        int dn = p * 4 + q, ci = j;
        if (co < 8 && dn < 11) val = t1c[(co * 8 + ci) * 11 + dn];
      } else {
        int dn = p * 2 + (q >> 1), ci = (q & 1) * 8 + j;
        const float* w = (s == 1) ? t2c : t3c;
        if (dn < 11) val = w[(co * 16 + ci) * 11 + dn];
      }
      f[j] = f2bf(val);
    }
    *(u8v*)&apk[(set * 64 + L) * 8] = f;
  }
#pragma unroll 1
  for (int ds = 0; ds < 7; ds++) {
    const float* w; int CIw, CIeff, kk;
    switch (ds) {
      case 0: w = t2d1; CIw = 8;  CIeff = 8;  kk = 0; break;
      case 1: w = t2d2; CIw = 16; CIeff = 16; kk = 0; break;
      case 2: w = t2d2; CIw = 16; CIeff = 16; kk = 1; break;
      case 3: w = t3d1; CIw = 16; CIeff = 16; kk = 0; break;
      case 4: w = t3d1; CIw = 16; CIeff = 16; kk = 1; break;
      case 5: w = t3d2; CIw = 16; CIeff = 16; kk = 0; break;
      default: w = t3d2; CIw = 16; CIeff = 16; kk = 1; break;
    }
    u8v f;
#pragma unroll
    for (int j = 0; j < 8; j++) {
      int kg = kk * 32 + q * 8 + j;
      int ci = kg % CIeff, jt = kg / CIeff;
      float val = (jt < 3) ? w[(co * CIw + ci) * 3 + jt] : 0.f;
      f[j] = f2bf(val);
    }
    *(u8v*)&apk[((15 + ds) * 64 + L) * 8] = f;
  }
}

// ---------------------------------------------------------------------------
// K2 (stage 1 only): fused d1+d2, proj folded, fp32 x input, bf16
// channel-interleaved output [by][n][t][8].
// ---------------------------------------------------------------------------
__global__ __launch_bounds__(128) void d12a_kernel(
    const float* __restrict__ xin,
    const float* __restrict__ pw, const float* __restrict__ pb,
    const float* __restrict__ w1,  // [8][4][3]
    const float* __restrict__ w2,  // [8][8][3]
    unsigned short* __restrict__ out, int b0) {
  constexpr int CI = 4, CO = 8, DIL = 1;
  const int t = threadIdx.x;
  const int n = swz_n(blockIdx.x), by = blockIdx.y;
  const int b = b0 + by;

  float r1[3][CO];
#pragma unroll
  for (int u = 0; u < 3; u++)
#pragma unroll
    for (int co = 0; co < CO; co++) r1[u][co] = 0.f;

  const float4* xp = (const float4*)xin + ((size_t)b * N + n) * T;
  float px[5][4];
#pragma unroll
  for (int v = 0; v < 5; v++) {
    int idx = t - v * DIL;
    float4 xr = xp[idx < 0 ? 0 : idx];
    bool ok = idx >= 0;
    px[v][0] = ok ? pb[0] + pw[0] * xr.x + pw[1] * xr.y + pw[2] * xr.z + pw[3] * xr.w : 0.f;
    px[v][1] = ok ? pb[1] + pw[4] * xr.x + pw[5] * xr.y + pw[6] * xr.z + pw[7] * xr.w : 0.f;
    px[v][2] = ok ? pb[2] + pw[8] * xr.x + pw[9] * xr.y + pw[10] * xr.z + pw[11] * xr.w : 0.f;
    px[v][3] = ok ? pb[3] + pw[12] * xr.x + pw[13] * xr.y + pw[14] * xr.z + pw[15] * xr.w : 0.f;
  }
#pragma unroll
  for (int ci = 0; ci < CI; ci++) {
#pragma unroll
    for (int j = 0; j < 3; j++) {
#pragma unroll
      for (int co = 0; co < CO; co++) {
        float w = w1[(co * CI + ci) * 3 + j];
#pragma unroll
        for (int u = 0; u < 3; u++) r1[u][co] += w * px[u + 2 - j][ci];
      }
    }
  }
#pragma unroll
  for (int u = 0; u < 3; u++)
#pragma unroll
    for (int co = 0; co < CO; co++) r1[u][co] = fmaxf(r1[u][co], 0.f);

  float acc[CO];
#pragma unroll
  for (int co = 0; co < CO; co++) acc[co] = 0.f;
#pragma unroll
  for (int cm = 0; cm < CO; cm++) {
#pragma unroll
    for (int j = 0; j < 3; j++) {
#pragma unroll
      for (int co = 0; co < CO; co++)
        acc[co] += w2[(co * CO + cm) * 3 + j] * r1[2 - j][cm];
    }
  }
  unsigned short* op = &out[(((size_t)by * N + n) * T + t) * CO];
  u8v a;
#pragma unroll
  for (int j = 0; j < 8; j++) a[j] = f2bf(fmaxf(acc[j], 0.f));
  *(u8v*)&op[0] = a;
}

// ---------------------------------------------------------------------------
// cd2: FUSED ccm (cross-stock 11x1 via MFMA, +residual) -> H, then the next
// stage's d1+d2 -> z. R10/R12 structure (measured-best chain): 128-thread
// blocks = two independent (n,by) jobs (wave wv handles by = blockIdx.y*2+wv).
//   C==8 : ccm t1 (NMF=3, x-proj residual), d12 stage2 (CI=8,  DIL=2)
//   C==16: ccm t2 (NMF=6, rw@H1 residual),  d12 stage3 (CI=16, DIL=4)
// ---------------------------------------------------------------------------
template <int C, int DIL>
__global__ __launch_bounds__(128) void cd2_kernel(
    const unsigned short* __restrict__ zin,   // [Bc][N][T][C] bf16
    const unsigned short* __restrict__ apkc,  // ccm A-frags [NMF][64][8]
    const unsigned short* __restrict__ apkd,  // d12 A-frags (d1 then d2)
    const void* __restrict__ resin,           // C==8: fp32 x; C==16: bf16 H1
    const float* __restrict__ rw,
    const float* __restrict__ pw, const float* __restrict__ pb,
    unsigned short* __restrict__ hout,        // [Bc][N][T][C] bf16
    unsigned short* __restrict__ zout,        // [Bc][N][T][16] bf16
    int b0) {
  constexpr int NMF = (C == 8) ? 3 : 6;
  constexpr int HALO = 8;
  __shared__ __align__(16) unsigned short Hs[2][HALO + T][C];
  __shared__ __align__(16) unsigned short Rs[2][HALO + T][16];
  const int wv = threadIdx.x >> 6;  // job within block
  const int wl = threadIdx.x & 63;  // lane within wave
  const int tcol = wl & 15, q = wl >> 4;
  const int n = swz_n(blockIdx.x);
  const int by = blockIdx.y * 2 + wv;
  const int b = b0 + by;

  // zero own halos (causal zero-pad; tap reach 2*DIL <= 8)
  if (wl < 16) {
    *(u8v*)&Rs[wv][wl >> 1][(wl & 1) * 8] = (u8v)0;
    if constexpr (C == 8) {
      if (wl < 8) *(u8v*)&Hs[wv][wl][0] = (u8v)0;
    } else {
      *(u8v*)&Hs[wv][wl >> 1][(wl & 1) * 8] = (u8v)0;
    }
  }

  // A fragments (64-lane patterns -> wl)
  s8v ac[NMF];
#pragma unroll
  for (int p = 0; p < NMF; p++) ac[p] = *(const s8v*)&apkc[(p * 64 + wl) * 8];
  constexpr int ND1 = (C == 8) ? 1 : 2;
  s8v a1_0 = *(const s8v*)&apkd[(0 * 64 + wl) * 8];
  s8v a1_1 = a1_0;
  if constexpr (C == 16) a1_1 = *(const s8v*)&apkd[(1 * 64 + wl) * 8];
  s8v a2_0 = *(const s8v*)&apkd[((ND1 + 0) * 64 + wl) * 8];
  s8v a2_1 = *(const s8v*)&apkd[((ND1 + 1) * 64 + wl) * 8];

  // ---- phase 1: ccm + residual -> H (global + LDS) ----
#pragma unroll 1
  for (int tt = 0; tt < 8; tt++) {
    const int t = tt * 16 + tcol;
    f4v d = (f4v)0.f;
#pragma unroll
    for (int p = 0; p < NMF; p++) {
      int dn = (C == 8) ? (p * 4 + q) : (p * 2 + (q >> 1));
      int row = n + dn - 5;
      bool ok = (unsigned)row < (unsigned)N;
      int rowc = ok ? row : 0;
      const unsigned short* bp =
          &zin[(((size_t)by * N + rowc) * T + t) * C + ((C == 16) ? (q & 1) * 8 : 0)];
      s8v bfrag = *(const s8v*)bp;
      if (!ok) bfrag = (s8v){0, 0, 0, 0, 0, 0, 0, 0};
      d = __builtin_amdgcn_mfma_f32_16x16x32_bf16(ac[p], bfrag, d, 0, 0, 0);
    }
    if constexpr (C == 8) {
      if (q < 2) {
        float4 xr = ((const float4*)resin)[((size_t)b * N + n) * T + t];
        float xv[4];
#pragma unroll
        for (int j = 0; j < 4; j++)
          xv[j] = pb[j] + pw[j * 4 + 0] * xr.x + pw[j * 4 + 1] * xr.y +
                  pw[j * 4 + 2] * xr.z + pw[j * 4 + 3] * xr.w;
        u4s hb16;
#pragma unroll
        for (int r = 0; r < 4; r++) {
          int co = q * 4 + r;
          float rv = rw[co * 4 + 0] * xv[0] + rw[co * 4 + 1] * xv[1] +
                     rw[co * 4 + 2] * xv[2] + rw[co * 4 + 3] * xv[3];
          hb16[r] = f2bf(fmaxf(rv + fmaxf(d[r], 0.f), 0.f));
        }
        *(u4s*)&hout[(((size_t)by * N + n) * T + t) * 8 + q * 4] = hb16;
        *(u4s*)&Hs[wv][HALO + t][q * 4] = hb16;
      }
    } else {
      const unsigned short* hp =
          (const unsigned short*)resin + (((size_t)by * N + n) * T + t) * 8;
      u8v hb = *(const u8v*)hp;  // H1: 8 channels
      float hv[8];
#pragma unroll
      for (int ci = 0; ci < 8; ci++) hv[ci] = bf2f(hb[ci]);
      u4s hb16;
#pragma unroll
      for (int r = 0; r < 4; r++) {
        int co = q * 4 + r;
        float rv = 0.f;
#pragma unroll
        for (int ci = 0; ci < 8; ci++) rv += rw[co * 8 + ci] * hv[ci];
        hb16[r] = f2bf(fmaxf(rv + fmaxf(d[r], 0.f), 0.f));
      }
      *(u4s*)&hout[(((size_t)by * N + n) * T + t) * 16 + q * 4] = hb16;
      *(u4s*)&Hs[wv][HALO + t][q * 4] = hb16;
    }
  }
  __syncthreads();

  // ---- phase 2: d1 from Hs -> Rs ----
#pragma unroll 2
  for (int tt = 0; tt < 8; tt++) {
    const int t = tt * 16 + tcol;
    f4v acc = (f4v)0.f;
    if constexpr (C == 8) {
      const int jt = (q < 3) ? q : 2;  // q==3 is A-zero pad
      s8v bf = *(const s8v*)&Hs[wv][HALO + t - DIL * jt][0];
      acc = __builtin_amdgcn_mfma_f32_16x16x32_bf16(a1_0, bf, acc, 0, 0, 0);
    } else {
      {
        const int jt = q >> 1, ci0 = (q & 1) * 8;
        s8v bf = *(const s8v*)&Hs[wv][HALO + t - DIL * jt][ci0];
        acc = __builtin_amdgcn_mfma_f32_16x16x32_bf16(a1_0, bf, acc, 0, 0, 0);
      }
      {
        const int ci0 = (q & 1) * 8;  // jt=2 for q<2; A-zero pad otherwise
        s8v bf = *(const s8v*)&Hs[wv][HALO + t - DIL * 2][ci0];
        acc = __builtin_amdgcn_mfma_f32_16x16x32_bf16(a1_1, bf, acc, 0, 0, 0);
      }
    }
    u4s rb;
#pragma unroll
    for (int r = 0; r < 4; r++) rb[r] = f2bf(fmaxf(acc[r], 0.f));
    *(u4s*)&Rs[wv][HALO + t][q * 4] = rb;
  }
  __syncthreads();

  // ---- phase 3: d2 from Rs -> zout ----
  unsigned short* opb = &zout[((size_t)by * N + n) * T * 16];
#pragma unroll 2
  for (int tt = 0; tt < 8; tt++) {
    const int t = tt * 16 + tcol;
    f4v acc = (f4v)0.f;
    {
      const int jt = q >> 1, ci0 = (q & 1) * 8;
      s8v bf = *(const s8v*)&Rs[wv][HALO + t - DIL * jt][ci0];
      acc = __builtin_amdgcn_mfma_f32_16x16x32_bf16(a2_0, bf, acc, 0, 0, 0);
    }
    {
      const int ci0 = (q & 1) * 8;
      s8v bf = *(const s8v*)&Rs[wv][HALO + t - DIL * 2][ci0];
      acc = __builtin_amdgcn_mfma_f32_16x16x32_bf16(a2_1, bf, acc, 0, 0, 0);
    }
    u4s ob;
#pragma unroll
    for (int r = 0; r < 4; r++) ob[r] = f2bf(fmaxf(acc[r], 0.f));
    *(u4s*)&opb[(size_t)t * 16 + q * 4] = ob;
  }
}

// ---------------------------------------------------------------------------
// cy: FUSED ccm t3 (identity residual) -> Y (fp32, LDS only) -> conv4 -> h4.
// R10/R12 structure: 128-thread blocks = two independent (n,by) jobs.
// R14: conv4 o-loop processed 4-at-a-time — the 16 shuffle-reduce trees are
// independent; interleaving 4 divides the exposed DS-op latency (~200 cyc
// per 6-level tree, previously 16 back-to-back serial trees) by ~4.
// Per-o math and reduce order bit-identical.
// ---------------------------------------------------------------------------
__global__ __launch_bounds__(128) void cy_kernel(
    const unsigned short* __restrict__ zin,   // Zb2b [Bc][N][T][16] bf16
    const unsigned short* __restrict__ apkc,  // sets 9..14
    const unsigned short* __restrict__ resin, // H2 [Bc][N][T][16] bf16
    const float* __restrict__ w4,             // [16][16][T]
    float* __restrict__ h4,                   // [B][16][N]
    int b0) {
  __shared__ __align__(16) float Ys[2][16][T + 2];
  const int wv = threadIdx.x >> 6;
  const int wl = threadIdx.x & 63;
  const int tcol = wl & 15, q = wl >> 4;
  const int n = swz_n(blockIdx.x);
  const int by = blockIdx.y * 2 + wv;
  const int b = b0 + by;

  s8v ac[6];
#pragma unroll
  for (int p = 0; p < 6; p++) ac[p] = *(const s8v*)&apkc[(p * 64 + wl) * 8];

  // ---- phase 1: ccm t3 -> Ys (fp32 LDS) ----
#pragma unroll 1
  for (int tt = 0; tt < 8; tt++) {
    const int t = tt * 16 + tcol;
    f4v d = (f4v)0.f;
#pragma unroll
    for (int p = 0; p < 6; p++) {
      int dn = p * 2 + (q >> 1);
      int row = n + dn - 5;
      bool ok = (unsigned)row < (unsigned)N;
      int rowc = ok ? row : 0;
      const unsigned short* bp =
          &zin[(((size_t)by * N + rowc) * T + t) * 16 + (q & 1) * 8];
      s8v bfrag = *(const s8v*)bp;
      if (!ok) bfrag = (s8v){0, 0, 0, 0, 0, 0, 0, 0};
      d = __builtin_amdgcn_mfma_f32_16x16x32_bf16(ac[p], bfrag, d, 0, 0, 0);
    }
    const unsigned short* hp = resin + (((size_t)by * N + n) * T + t) * 16 + q * 4;
    u4s hb = *(const u4s*)hp;
#pragma unroll
    for (int r = 0; r < 4; r++)
      Ys[wv][q * 4 + r][t] = fmaxf(bf2f(hb[r]) + fmaxf(d[r], 0.f), 0.f);
  }
  __syncthreads();

  // ---- phase 2: conv4; o processed 4-wide (interleaved reduce trees) ----
  const int t0 = wl * 2;
  vf2 y[16];
#pragma unroll
  for (int ci = 0; ci < 16; ci++) y[ci] = *(const vf2*)&Ys[wv][ci][t0];

#pragma unroll 1
  for (int ob = 0; ob < 16; ob += 4) {
    float sum[4];
#pragma unroll
    for (int oo = 0; oo < 4; oo++) {
      const int o = ob + oo;
      vf2 s = (vf2)0.f;
#pragma unroll
      for (int ci = 0; ci < 16; ci++) {
        vf2 w = *(const vf2*)&w4[(size_t)(o * 16 + ci) * T + t0];
        s += w * y[ci];
      }
      sum[oo] = s.x + s.y;
    }
#pragma unroll
    for (int off = 32; off > 0; off >>= 1) {
#pragma unroll
      for (int oo = 0; oo < 4; oo++) sum[oo] += __shfl_down(sum[oo], off);
    }
    if (wl == 0) {
#pragma unroll
      for (int oo = 0; oo < 4; oo++)
        h4[((size_t)b * 16 + ob + oo) * N + n] = fmaxf(sum[oo], 0.f);
    }
  }
}

// ---------------------------------------------------------------------------
// K8: logits (torch reshape scramble) + softmax over N
// ---------------------------------------------------------------------------
__global__ __launch_bounds__(128) void final_kernel(
    const float* __restrict__ hl, const float* __restrict__ h4,
    const float* __restrict__ ow, const float* __restrict__ ob,
    float* __restrict__ out) {
  __shared__ float red[128];
  int b = blockIdx.x, n = threadIdx.x;
  bool valid = n < N;
  float lv = 0.f;
  if (valid) {
    int idx = b * N + n;
    int sb = idx & (B - 1);
    int sn = idx >> 8;
    const float* h = &hl[((size_t)sb * N + sn) * 16];
    float a = ob[0];
#pragma unroll
    for (int k = 0; k < 16; k++) a += h[k] * ow[k];
#pragma unroll
    for (int c = 0; c < 16; c++) a += h4[((size_t)b * 16 + c) * N + n] * ow[16 + c];
    lv = a;
  }
  red[n] = valid ? lv : -1e30f;
  __syncthreads();
  for (int off = 64; off > 0; off >>= 1) {
    if (n < off) red[n] = fmaxf(red[n], red[n + off]);
    __syncthreads();
  }
  float m = red[0];
  __syncthreads();
  float e = valid ? __expf(lv - m) : 0.f;
  red[n] = e;
  __syncthreads();
  for (int off = 64; off > 0; off >>= 1) {
    if (n < off) red[n] += red[n + off];
    __syncthreads();
  }
  float s = red[0];
  if (valid) out[(size_t)b * N + n] = e / s;
}

// ---------------------------------------------------------------------------
// Launch. Chunked over B (R12 config — Bc as large as the workspace allows;
// the R13 Bc<=32 experiment cost ~170 us in extra dispatch overhead).
// Buffers (all bf16 interleaved [Bc][N][T][C]): Zb1(4) + H1b(4) + Zb2a(8) +
// H2b(8) + Zb2b(8) = 32 NT-floats per b.
// ---------------------------------------------------------------------------
extern "C" void kernel_launch(void* const* d_in, const int* in_sizes, int n_in,
                              void* d_out, int out_size, void* d_ws, size_t ws_size,
                              hipStream_t stream) {
  const float* x    = (const float*)d_in[0];
  const float* pw   = (const float*)d_in[1];
  const float* pb   = (const float*)d_in[2];
  const float* w_ih = (const float*)d_in[3];
  const float* w_hh = (const float*)d_in[4];
  const float* b_ih = (const float*)d_in[5];
  const float* b_hh = (const float*)d_in[6];
  const float* t1d1 = (const float*)d_in[7];
  const float* t1d2 = (const float*)d_in[8];
  const float* t1c  = (const float*)d_in[9];
  const float* t1r  = (const float*)d_in[10];
  const float* t2d1 = (const float*)d_in[11];
  const float* t2d2 = (const float*)d_in[12];
  const float* t2c  = (const float*)d_in[13];
  const float* t2r  = (const float*)d_in[14];
  const float* t3d1 = (const float*)d_in[15];
  const float* t3d2 = (const float*)d_in[16];
  const float* t3c  = (const float*)d_in[17];
  const float* w4   = (const float*)d_in[18];
  const float* ow   = (const float*)d_in[19];
  const float* ob   = (const float*)d_in[20];
  float* outp = (float*)d_out;

  const size_t NT = (size_t)N * T;            // 12928
  const size_t Bn16 = (size_t)B * N * 16;
  const size_t unit = 32 * NT;                // floats per chunked b
  const size_t fixed = 2 * Bn16 + 8192;       // hl + h4 + apk

  int Bc = 4;
  const int cands[7] = {256, 128, 64, 32, 16, 8, 4};
  for (int i = 0; i < 7; i++) {
    if ((cands[i] * unit + fixed) * sizeof(float) <= ws_size) { Bc = cands[i]; break; }
  }

  float* ws = (float*)d_ws;
  float* hl = ws;                              // [B*N][16]
  float* h4 = hl + Bn16;                       // [B][16][N]
  unsigned short* apk = (unsigned short*)(h4 + Bn16);  // 22*512 ushorts
  float* p = h4 + Bn16 + 8192;
  unsigned short* Zb1  = (unsigned short*)p; p += (size_t)Bc * 4 * NT;
  unsigned short* H1b  = (unsigned short*)p; p += (size_t)Bc * 4 * NT;
  unsigned short* Zb2a = (unsigned short*)p; p += (size_t)Bc * 8 * NT;
  unsigned short* H2b  = (unsigned short*)p; p += (size_t)Bc * 8 * NT;
  unsigned short* Zb2b = (unsigned short*)p;

  prep_kernel<<<1, 64, 0, stream>>>(t1c, t2c, t3c, t2d1, t2d2, t3d1, t3d2, apk);
  lstm_kernel<<<(B * N) / 16, 64, 0, stream>>>(x, pw, pb, w_ih, w_hh, b_ih,
                                               b_hh, hl);

  dim3 g(N, Bc);
  dim3 g2(N, Bc / 2);
  for (int b0 = 0; b0 < B; b0 += Bc) {
    d12a_kernel<<<g, 128, 0, stream>>>(x, pw, pb, t1d1, t1d2, Zb1, b0);
    cd2_kernel<8, 2><<<g2, 128, 0, stream>>>(
        Zb1, apk + 0 * 512, apk + 15 * 512, x, t1r, pw, pb, H1b, Zb2a, b0);
    cd2_kernel<16, 4><<<g2, 128, 0, stream>>>(
        Zb2a, apk + 3 * 512, apk + 18 * 512, H1b, t2r, pw, pb, H2b, Zb2b, b0);
    cy_kernel<<<g2, 128, 0, stream>>>(Zb2b, apk + 9 * 512, H2b, w4, h4, b0);
  }

  final_kernel<<<B, 128, 0, stream>>>(hl, h4, ow, ob, outp);
}

// Round 15
// 707.748 us; speedup vs baseline: 1.2719x; 1.0254x over previous
//
#include <hip/hip_runtime.h>
#include <hip/hip_bf16.h>

// ---------------------------------------------------------------------------
// Problem constants (reference: B,N,T,P,H = 256,101,128,4,16)
// ---------------------------------------------------------------------------
constexpr int B = 256;
constexpr int N = 101;
constexpr int T = 128;

typedef float vf2 __attribute__((ext_vector_type(2)));
typedef short s8v __attribute__((ext_vector_type(8)));    // 8 bf16 (4 VGPRs)
typedef unsigned short u8v __attribute__((ext_vector_type(8)));
typedef unsigned short u4s __attribute__((ext_vector_type(4)));
typedef unsigned int u32x4 __attribute__((ext_vector_type(4)));
typedef float f4v __attribute__((ext_vector_type(4)));    // MFMA accum

__device__ __forceinline__ float frcp(float x) { return __builtin_amdgcn_rcpf(x); }
__device__ __forceinline__ float sigmoidf_(float x) { return frcp(1.f + __expf(-x)); }
__device__ __forceinline__ float tanhf_(float x) { return 2.f * frcp(1.f + __expf(-2.f * x)) - 1.f; }

// fp32 -> bf16 bits, round-nearest-even
__device__ __forceinline__ unsigned short f2bf(float x) {
  unsigned int u = __float_as_uint(x);
  u = (u + 0x7FFFu + ((u >> 16) & 1u)) >> 16;
  return (unsigned short)u;
}
// bf16 bits -> fp32
__device__ __forceinline__ float bf2f(unsigned short u) {
  return __uint_as_float((unsigned int)u << 16);
}
__device__ __forceinline__ unsigned pack2(float a, float b) {
  return (unsigned)f2bf(a) | ((unsigned)f2bf(b) << 16);
}

// XCD-aware n-swizzle. Bijection on [0,101). Blocks L and L+8 (consecutive n)
// land on the same XCD -> the ccm n±5 gather stays mostly XCD-local.
__device__ __forceinline__ int swz_n(int L) {
  int q = L & 7, r = L >> 3;
  return q * 13 - (q > 5 ? (q - 5) : 0) + r;
}

// ---------------------------------------------------------------------------
// K1: LSTM via MFMA, shuffle-free recurrence (R12/R13, measured ~116 us).
// Explicit one-step Xs prefetch; bit-identical values.
// ---------------------------------------------------------------------------
__global__ __launch_bounds__(64) void lstm_kernel(
    const float* __restrict__ x, const float* __restrict__ pw,
    const float* __restrict__ pb, const float* __restrict__ w_ih,
    const float* __restrict__ w_hh, const float* __restrict__ b_ih,
    const float* __restrict__ b_hh, float* __restrict__ h_out) {
  __shared__ __align__(16) unsigned int Xs[T][16][2];  // 16 KB
  const int l = threadIdx.x;
  const int s = l & 15;       // seq within wave (B col); also A-row index
  const int q = l >> 4;       // k-group / D-row group
  const int row0 = blockIdx.x * 16;

  // ---- A fragments (one-time): gate j = m*16 + s, k = q*8+j2 ----
  // k-layout: j2<4 -> W_hh[j][q*4+j2] (lane-local h); j2>=4 -> q==0 ? Wf : 0
  s8v Afr[4];
#pragma unroll
  for (int m = 0; m < 4; m++) {
    const int j = m * 16 + s;
    float wfm[4];
#pragma unroll
    for (int p = 0; p < 4; p++) {
      float v = 0.f;
#pragma unroll
      for (int c = 0; c < 4; c++) v += w_ih[j * 4 + c] * pw[c * 4 + p];
      wfm[p] = v;
    }
    u8v av;
#pragma unroll
    for (int j2 = 0; j2 < 8; j2++) {
      float val;
      if (j2 < 4) val = w_hh[j * 16 + (q * 4 + j2)];
      else val = (q == 0) ? wfm[j2 - 4] : 0.f;
      av[j2] = f2bf(val);
    }
    Afr[m] = *(s8v*)&av;
  }
  // ---- bias (fp32, added post-MFMA): gate jb = m*16 + q*4 + r ----
  float bi[4][4];
#pragma unroll
  for (int m = 0; m < 4; m++) {
#pragma unroll
    for (int r = 0; r < 4; r++) {
      const int jb = m * 16 + q * 4 + r;
      float bp = b_ih[jb] + b_hh[jb];
#pragma unroll
      for (int c = 0; c < 4; c++) bp += w_ih[jb * 4 + c] * pb[c];
      bi[m][r] = bp;
    }
  }

  // ---- stage x -> LDS (one time; lane covers seq s at t = q + 4i) ----
  const float4* xp0 = (const float4*)x + (size_t)row0 * T;
#pragma unroll 8
  for (int i = 0; i < 32; i++) {
    const int t = q + i * 4;
    float4 v = xp0[(size_t)s * T + t];
    Xs[t][s][0] = pack2(v.x, v.y);
    Xs[t][s][1] = pack2(v.z, v.w);
  }
  __syncthreads();  // 1-wave block: compiles to waitcnt (free)

  float c0 = 0.f, c1 = 0.f, c2 = 0.f, c3 = 0.f;
  float h0 = 0.f, h1 = 0.f, h2 = 0.f, h3 = 0.f;
  unsigned X0c = Xs[0][s][0], X1c = Xs[0][s][1];

#pragma unroll 1
  for (int t = 0; t < T; t++) {
    // prefetch next step's x words (off the critical path)
    const int tn = (t + 1 < T) ? t + 1 : t;
    unsigned X0n = Xs[tn][s][0];
    unsigned X1n = Xs[tn][s][1];

    // ---- build B fragment: all lane-local ----
    unsigned b0 = pack2(h0, h1);
    unsigned b1 = pack2(h2, h3);
    unsigned b2 = (q == 0) ? X0c : 0u;
    unsigned b3 = (q == 0) ? X1c : 0u;
    u32x4 bu = {b0, b1, b2, b3};
    s8v Bfr = *(s8v*)&bu;

    // ---- 4 MFMAs: gate pre-activations ----
    f4v d0 = __builtin_amdgcn_mfma_f32_16x16x32_bf16(Afr[0], Bfr, (f4v)0.f, 0, 0, 0);
    f4v d1 = __builtin_amdgcn_mfma_f32_16x16x32_bf16(Afr[1], Bfr, (f4v)0.f, 0, 0, 0);
    f4v d2 = __builtin_amdgcn_mfma_f32_16x16x32_bf16(Afr[2], Bfr, (f4v)0.f, 0, 0, 0);
    f4v d3 = __builtin_amdgcn_mfma_f32_16x16x32_bf16(Afr[3], Bfr, (f4v)0.f, 0, 0, 0);

    // ---- lane-local c/h update (fp32) ----
    float iv, fv, gv, ov;
    iv = sigmoidf_(d0[0] + bi[0][0]); fv = sigmoidf_(d1[0] + bi[1][0]);
    gv = tanhf_(d2[0] + bi[2][0]);    ov = sigmoidf_(d3[0] + bi[3][0]);
    c0 = fv * c0 + iv * gv;           h0 = ov * tanhf_(c0);
    iv = sigmoidf_(d0[1] + bi[0][1]); fv = sigmoidf_(d1[1] + bi[1][1]);
    gv = tanhf_(d2[1] + bi[2][1]);    ov = sigmoidf_(d3[1] + bi[3][1]);
    c1 = fv * c1 + iv * gv;           h1 = ov * tanhf_(c1);
    iv = sigmoidf_(d0[2] + bi[0][2]); fv = sigmoidf_(d1[2] + bi[1][2]);
    gv = tanhf_(d2[2] + bi[2][2]);    ov = sigmoidf_(d3[2] + bi[3][2]);
    c2 = fv * c2 + iv * gv;           h2 = ov * tanhf_(c2);
    iv = sigmoidf_(d0[3] + bi[0][3]); fv = sigmoidf_(d1[3] + bi[1][3]);
    gv = tanhf_(d2[3] + bi[2][3]);    ov = sigmoidf_(d3[3] + bi[3][3]);
    c3 = fv * c3 + iv * gv;           h3 = ov * tanhf_(c3);

    X0c = X0n;
    X1c = X1n;
  }
  float* op = &h_out[(size_t)(row0 + s) * 16 + q * 4];
  op[0] = h0; op[1] = h1; op[2] = h2; op[3] = h3;
}

// ---------------------------------------------------------------------------
// Prep: pack conv weights into MFMA A-fragment order (bf16).
// Sets 0..14: cc convs. Sets 15..21: d1/d2 of stages 2/3 (K=jt*CIeff+ci,
// zero-padded past K=3*CIeff so the B pad region needs no masking):
//   15: s2 d1 (CIw=8)   16,17: s2 d2   18,19: s3 d1   20,21: s3 d2
// ---------------------------------------------------------------------------
__global__ void prep_kernel(const float* __restrict__ t1c,
                            const float* __restrict__ t2c,
                            const float* __restrict__ t3c,
                            const float* __restrict__ t2d1,
                            const float* __restrict__ t2d2,
                            const float* __restrict__ t3d1,
                            const float* __restrict__ t3d2,
                            unsigned short* __restrict__ apk) {
  const int L = threadIdx.x;  // 64 threads
  const int co = L & 15, q = L >> 4;
#pragma unroll 1
  for (int set = 0; set < 15; set++) {
    int s, p;
    if (set < 3) { s = 0; p = set; }
    else if (set < 9) { s = 1; p = set - 3; }
    else { s = 2; p = set - 9; }
    u8v f;
#pragma unroll
    for (int j = 0; j < 8; j++) {
      float val = 0.f;
      if (s == 0) {
        int dn = p * 4 + q, ci = j;
        if (co < 8 && dn < 11) val = t1c[(co * 8 + ci) * 11 + dn];
      } else {
        int dn = p * 2 + (q >> 1), ci = (q & 1) * 8 + j;
        const float* w = (s == 1) ? t2c : t3c;
        if (dn < 11) val = w[(co * 16 + ci) * 11 + dn];
      }
      f[j] = f2bf(val);
    }
    *(u8v*)&apk[(set * 64 + L) * 8] = f;
  }
#pragma unroll 1
  for (int ds = 0; ds < 7; ds++) {
    const float* w; int CIw, CIeff, kk;
    switch (ds) {
      case 0: w = t2d1; CIw = 8;  CIeff = 8;  kk = 0; break;
      case 1: w = t2d2; CIw = 16; CIeff = 16; kk = 0; break;
      case 2: w = t2d2; CIw = 16; CIeff = 16; kk = 1; break;
      case 3: w = t3d1; CIw = 16; CIeff = 16; kk = 0; break;
      case 4: w = t3d1; CIw = 16; CIeff = 16; kk = 1; break;
      case 5: w = t3d2; CIw = 16; CIeff = 16; kk = 0; break;
      default: w = t3d2; CIw = 16; CIeff = 16; kk = 1; break;
    }
    u8v f;
#pragma unroll
    for (int j = 0; j < 8; j++) {
      int kg = kk * 32 + q * 8 + j;
      int ci = kg % CIeff, jt = kg / CIeff;
      float val = (jt < 3) ? w[(co * CIw + ci) * 3 + jt] : 0.f;
      f[j] = f2bf(val);
    }
    *(u8v*)&apk[((15 + ds) * 64 + L) * 8] = f;
  }
}

// ---------------------------------------------------------------------------
// K2 (stage 1 only): fused d1+d2, proj folded, fp32 x input, bf16
// channel-interleaved output [by][n][t][8].
// R15: also emits xp = proj(x) as bf16 [by][n][t][4] so cd2<8> never has to
// re-read the fp32 x (53 MB -> 13 MB residual traffic).
// ---------------------------------------------------------------------------
__global__ __launch_bounds__(128) void d12a_kernel(
    const float* __restrict__ xin,
    const float* __restrict__ pw, const float* __restrict__ pb,
    const float* __restrict__ w1,  // [8][4][3]
    const float* __restrict__ w2,  // [8][8][3]
    unsigned short* __restrict__ out,
    unsigned short* __restrict__ xpb,  // [Bc][N][T][4] bf16 proj(x)
    int b0) {
  constexpr int CI = 4, CO = 8, DIL = 1;
  const int t = threadIdx.x;
  const int n = swz_n(blockIdx.x), by = blockIdx.y;
  const int b = b0 + by;

  float r1[3][CO];
#pragma unroll
  for (int u = 0; u < 3; u++)
#pragma unroll
    for (int co = 0; co < CO; co++) r1[u][co] = 0.f;

  const float4* xp = (const float4*)xin + ((size_t)b * N + n) * T;
  float px[5][4];
#pragma unroll
  for (int v = 0; v < 5; v++) {
    int idx = t - v * DIL;
    float4 xr = xp[idx < 0 ? 0 : idx];
    bool ok = idx >= 0;
    px[v][0] = ok ? pb[0] + pw[0] * xr.x + pw[1] * xr.y + pw[2] * xr.z + pw[3] * xr.w : 0.f;
    px[v][1] = ok ? pb[1] + pw[4] * xr.x + pw[5] * xr.y + pw[6] * xr.z + pw[7] * xr.w : 0.f;
    px[v][2] = ok ? pb[2] + pw[8] * xr.x + pw[9] * xr.y + pw[10] * xr.z + pw[11] * xr.w : 0.f;
    px[v][3] = ok ? pb[3] + pw[12] * xr.x + pw[13] * xr.y + pw[14] * xr.z + pw[15] * xr.w : 0.f;
  }
  // xp pass-through: proj(x) at tap v=0 is exactly proj(x[t])
  u4s xq;
#pragma unroll
  for (int j = 0; j < 4; j++) xq[j] = f2bf(px[0][j]);
  *(u4s*)&xpb[(((size_t)by * N + n) * T + t) * 4] = xq;

#pragma unroll
  for (int ci = 0; ci < CI; ci++) {
#pragma unroll
    for (int j = 0; j < 3; j++) {
#pragma unroll
      for (int co = 0; co < CO; co++) {
        float w = w1[(co * CI + ci) * 3 + j];
#pragma unroll
        for (int u = 0; u < 3; u++) r1[u][co] += w * px[u + 2 - j][ci];
      }
    }
  }
#pragma unroll
  for (int u = 0; u < 3; u++)
#pragma unroll
    for (int co = 0; co < CO; co++) r1[u][co] = fmaxf(r1[u][co], 0.f);

  float acc[CO];
#pragma unroll
  for (int co = 0; co < CO; co++) acc[co] = 0.f;
#pragma unroll
  for (int cm = 0; cm < CO; cm++) {
#pragma unroll
    for (int j = 0; j < 3; j++) {
#pragma unroll
      for (int co = 0; co < CO; co++)
        acc[co] += w2[(co * CO + cm) * 3 + j] * r1[2 - j][cm];
    }
  }
  unsigned short* op = &out[(((size_t)by * N + n) * T + t) * CO];
  u8v a;
#pragma unroll
  for (int j = 0; j < 8; j++) a[j] = f2bf(fmaxf(acc[j], 0.f));
  *(u8v*)&op[0] = a;
}

// ---------------------------------------------------------------------------
// cd2: FUSED ccm (cross-stock 11x1 via MFMA, +residual) -> H, then the next
// stage's d1+d2 -> z. R10/R12 structure: 128-thread blocks = two independent
// (n,by) jobs (wave wv handles by = blockIdx.y*2+wv).
//   C==8 : ccm t1 (NMF=3, residual from PRE-PROJECTED xp bf16 — R15),
//          d12 stage2 (CI=8,  DIL=2)
//   C==16: ccm t2 (NMF=6, rw@H1 residual),  d12 stage3 (CI=16, DIL=4)
// ---------------------------------------------------------------------------
template <int C, int DIL>
__global__ __launch_bounds__(128) void cd2_kernel(
    const unsigned short* __restrict__ zin,   // [Bc][N][T][C] bf16
    const unsigned short* __restrict__ apkc,  // ccm A-frags [NMF][64][8]
    const unsigned short* __restrict__ apkd,  // d12 A-frags (d1 then d2)
    const void* __restrict__ resin,           // C==8: bf16 xp; C==16: bf16 H1
    const float* __restrict__ rw,
    unsigned short* __restrict__ hout,        // [Bc][N][T][C] bf16
    unsigned short* __restrict__ zout,        // [Bc][N][T][16] bf16
    int b0) {
  constexpr int NMF = (C == 8) ? 3 : 6;
  constexpr int HALO = 8;
  __shared__ __align__(16) unsigned short Hs[2][HALO + T][C];
  __shared__ __align__(16) unsigned short Rs[2][HALO + T][16];
  const int wv = threadIdx.x >> 6;  // job within block
  const int wl = threadIdx.x & 63;  // lane within wave
  const int tcol = wl & 15, q = wl >> 4;
  const int n = swz_n(blockIdx.x);
  const int by = blockIdx.y * 2 + wv;

  // zero own halos (causal zero-pad; tap reach 2*DIL <= 8)
  if (wl < 16) {
    *(u8v*)&Rs[wv][wl >> 1][(wl & 1) * 8] = (u8v)0;
    if constexpr (C == 8) {
      if (wl < 8) *(u8v*)&Hs[wv][wl][0] = (u8v)0;
    } else {
      *(u8v*)&Hs[wv][wl >> 1][(wl & 1) * 8] = (u8v)0;
    }
  }

  // A fragments (64-lane patterns -> wl)
  s8v ac[NMF];
#pragma unroll
  for (int p = 0; p < NMF; p++) ac[p] = *(const s8v*)&apkc[(p * 64 + wl) * 8];
  constexpr int ND1 = (C == 8) ? 1 : 2;
  s8v a1_0 = *(const s8v*)&apkd[(0 * 64 + wl) * 8];
  s8v a1_1 = a1_0;
  if constexpr (C == 16) a1_1 = *(const s8v*)&apkd[(1 * 64 + wl) * 8];
  s8v a2_0 = *(const s8v*)&apkd[((ND1 + 0) * 64 + wl) * 8];
  s8v a2_1 = *(const s8v*)&apkd[((ND1 + 1) * 64 + wl) * 8];

  // ---- phase 1: ccm + residual -> H (global + LDS) ----
#pragma unroll 1
  for (int tt = 0; tt < 8; tt++) {
    const int t = tt * 16 + tcol;
    f4v d = (f4v)0.f;
#pragma unroll
    for (int p = 0; p < NMF; p++) {
      int dn = (C == 8) ? (p * 4 + q) : (p * 2 + (q >> 1));
      int row = n + dn - 5;
      bool ok = (unsigned)row < (unsigned)N;
      int rowc = ok ? row : 0;
      const unsigned short* bp =
          &zin[(((size_t)by * N + rowc) * T + t) * C + ((C == 16) ? (q & 1) * 8 : 0)];
      s8v bfrag = *(const s8v*)bp;
      if (!ok) bfrag = (s8v){0, 0, 0, 0, 0, 0, 0, 0};
      d = __builtin_amdgcn_mfma_f32_16x16x32_bf16(ac[p], bfrag, d, 0, 0, 0);
    }
    if constexpr (C == 8) {
      if (q < 2) {
        const unsigned short* xp8 =
            (const unsigned short*)resin + (((size_t)by * N + n) * T + t) * 4;
        u4s xr4 = *(const u4s*)xp8;
        float xv[4];
#pragma unroll
        for (int j = 0; j < 4; j++) xv[j] = bf2f(xr4[j]);
        u4s hb16;
#pragma unroll
        for (int r = 0; r < 4; r++) {
          int co = q * 4 + r;
          float rv = rw[co * 4 + 0] * xv[0] + rw[co * 4 + 1] * xv[1] +
                     rw[co * 4 + 2] * xv[2] + rw[co * 4 + 3] * xv[3];
          hb16[r] = f2bf(fmaxf(rv + fmaxf(d[r], 0.f), 0.f));
        }
        *(u4s*)&hout[(((size_t)by * N + n) * T + t) * 8 + q * 4] = hb16;
        *(u4s*)&Hs[wv][HALO + t][q * 4] = hb16;
      }
    } else {
      const unsigned short* hp =
          (const unsigned short*)resin + (((size_t)by * N + n) * T + t) * 8;
      u8v hb = *(const u8v*)hp;  // H1: 8 channels
      float hv[8];
#pragma unroll
      for (int ci = 0; ci < 8; ci++) hv[ci] = bf2f(hb[ci]);
      u4s hb16;
#pragma unroll
      for (int r = 0; r < 4; r++) {
        int co = q * 4 + r;
        float rv = 0.f;
#pragma unroll
        for (int ci = 0; ci < 8; ci++) rv += rw[co * 8 + ci] * hv[ci];
        hb16[r] = f2bf(fmaxf(rv + fmaxf(d[r], 0.f), 0.f));
      }
      *(u4s*)&hout[(((size_t)by * N + n) * T + t) * 16 + q * 4] = hb16;
      *(u4s*)&Hs[wv][HALO + t][q * 4] = hb16;
    }
  }
  __syncthreads();

  // ---- phase 2: d1 from Hs -> Rs ----
#pragma unroll 2
  for (int tt = 0; tt < 8; tt++) {
    const int t = tt * 16 + tcol;
    f4v acc = (f4v)0.f;
    if constexpr (C == 8) {
      const int jt = (q < 3) ? q : 2;  // q==3 is A-zero pad
      s8v bf = *(const s8v*)&Hs[wv][HALO + t - DIL * jt][0];
      acc = __builtin_amdgcn_mfma_f32_16x16x32_bf16(a1_0, bf, acc, 0, 0, 0);
    } else {
      {
        const int jt = q >> 1, ci0 = (q & 1) * 8;
        s8v bf = *(const s8v*)&Hs[wv][HALO + t - DIL * jt][ci0];
        acc = __builtin_amdgcn_mfma_f32_16x16x32_bf16(a1_0, bf, acc, 0, 0, 0);
      }
      {
        const int ci0 = (q & 1) * 8;  // jt=2 for q<2; A-zero pad otherwise
        s8v bf = *(const s8v*)&Hs[wv][HALO + t - DIL * 2][ci0];
        acc = __builtin_amdgcn_mfma_f32_16x16x32_bf16(a1_1, bf, acc, 0, 0, 0);
      }
    }
    u4s rb;
#pragma unroll
    for (int r = 0; r < 4; r++) rb[r] = f2bf(fmaxf(acc[r], 0.f));
    *(u4s*)&Rs[wv][HALO + t][q * 4] = rb;
  }
  __syncthreads();

  // ---- phase 3: d2 from Rs -> zout ----
  unsigned short* opb = &zout[((size_t)by * N + n) * T * 16];
#pragma unroll 2
  for (int tt = 0; tt < 8; tt++) {
    const int t = tt * 16 + tcol;
    f4v acc = (f4v)0.f;
    {
      const int jt = q >> 1, ci0 = (q & 1) * 8;
      s8v bf = *(const s8v*)&Rs[wv][HALO + t - DIL * jt][ci0];
      acc = __builtin_amdgcn_mfma_f32_16x16x32_bf16(a2_0, bf, acc, 0, 0, 0);
    }
    {
      const int ci0 = (q & 1) * 8;
      s8v bf = *(const s8v*)&Rs[wv][HALO + t - DIL * 2][ci0];
      acc = __builtin_amdgcn_mfma_f32_16x16x32_bf16(a2_1, bf, acc, 0, 0, 0);
    }
    u4s ob;
#pragma unroll
    for (int r = 0; r < 4; r++) ob[r] = f2bf(fmaxf(acc[r], 0.f));
    *(u4s*)&opb[(size_t)t * 16 + q * 4] = ob;
  }
}

// ---------------------------------------------------------------------------
// cy: FUSED ccm t3 (identity residual) -> Y (fp32, LDS only) -> conv4 -> h4.
// R10/R14 structure: 128-thread blocks = two independent (n,by) jobs;
// conv4 o-loop 4-wide interleaved reduce trees.
// ---------------------------------------------------------------------------
__global__ __launch_bounds__(128) void cy_kernel(
    const unsigned short* __restrict__ zin,   // Zb2b [Bc][N][T][16] bf16
    const unsigned short* __restrict__ apkc,  // sets 9..14
    const unsigned short* __restrict__ resin, // H2 [Bc][N][T][16] bf16
    const float* __restrict__ w4,             // [16][16][T]
    float* __restrict__ h4,                   // [B][16][N]
    int b0) {
  __shared__ __align__(16) float Ys[2][16][T + 2];
  const int wv = threadIdx.x >> 6;
  const int wl = threadIdx.x & 63;
  const int tcol = wl & 15, q = wl >> 4;
  const int n = swz_n(blockIdx.x);
  const int by = blockIdx.y * 2 + wv;
  const int b = b0 + by;

  s8v ac[6];
#pragma unroll
  for (int p = 0; p < 6; p++) ac[p] = *(const s8v*)&apkc[(p * 64 + wl) * 8];

  // ---- phase 1: ccm t3 -> Ys (fp32 LDS) ----
#pragma unroll 1
  for (int tt = 0; tt < 8; tt++) {
    const int t = tt * 16 + tcol;
    f4v d = (f4v)0.f;
#pragma unroll
    for (int p = 0; p < 6; p++) {
      int dn = p * 2 + (q >> 1);
      int row = n + dn - 5;
      bool ok = (unsigned)row < (unsigned)N;
      int rowc = ok ? row : 0;
      const unsigned short* bp =
          &zin[(((size_t)by * N + rowc) * T + t) * 16 + (q & 1) * 8];
      s8v bfrag = *(const s8v*)bp;
      if (!ok) bfrag = (s8v){0, 0, 0, 0, 0, 0, 0, 0};
      d = __builtin_amdgcn_mfma_f32_16x16x32_bf16(ac[p], bfrag, d, 0, 0, 0);
    }
    const unsigned short* hp = resin + (((size_t)by * N + n) * T + t) * 16 + q * 4;
    u4s hb = *(const u4s*)hp;
#pragma unroll
    for (int r = 0; r < 4; r++)
      Ys[wv][q * 4 + r][t] = fmaxf(bf2f(hb[r]) + fmaxf(d[r], 0.f), 0.f);
  }
  __syncthreads();

  // ---- phase 2: conv4; o processed 4-wide (interleaved reduce trees) ----
  const int t0 = wl * 2;
  vf2 y[16];
#pragma unroll
  for (int ci = 0; ci < 16; ci++) y[ci] = *(const vf2*)&Ys[wv][ci][t0];

#pragma unroll 1
  for (int ob = 0; ob < 16; ob += 4) {
    float sum[4];
#pragma unroll
    for (int oo = 0; oo < 4; oo++) {
      const int o = ob + oo;
      vf2 s = (vf2)0.f;
#pragma unroll
      for (int ci = 0; ci < 16; ci++) {
        vf2 w = *(const vf2*)&w4[(size_t)(o * 16 + ci) * T + t0];
        s += w * y[ci];
      }
      sum[oo] = s.x + s.y;
    }
#pragma unroll
    for (int off = 32; off > 0; off >>= 1) {
#pragma unroll
      for (int oo = 0; oo < 4; oo++) sum[oo] += __shfl_down(sum[oo], off);
    }
    if (wl == 0) {
#pragma unroll
      for (int oo = 0; oo < 4; oo++)
        h4[((size_t)b * 16 + ob + oo) * N + n] = fmaxf(sum[oo], 0.f);
    }
  }
}

// ---------------------------------------------------------------------------
// K8: logits (torch reshape scramble) + softmax over N
// ---------------------------------------------------------------------------
__global__ __launch_bounds__(128) void final_kernel(
    const float* __restrict__ hl, const float* __restrict__ h4,
    const float* __restrict__ ow, const float* __restrict__ ob,
    float* __restrict__ out) {
  __shared__ float red[128];
  int b = blockIdx.x, n = threadIdx.x;
  bool valid = n < N;
  float lv = 0.f;
  if (valid) {
    int idx = b * N + n;
    int sb = idx & (B - 1);
    int sn = idx >> 8;
    const float* h = &hl[((size_t)sb * N + sn) * 16];
    float a = ob[0];
#pragma unroll
    for (int k = 0; k < 16; k++) a += h[k] * ow[k];
#pragma unroll
    for (int c = 0; c < 16; c++) a += h4[((size_t)b * 16 + c) * N + n] * ow[16 + c];
    lv = a;
  }
  red[n] = valid ? lv : -1e30f;
  __syncthreads();
  for (int off = 64; off > 0; off >>= 1) {
    if (n < off) red[n] = fmaxf(red[n], red[n + off]);
    __syncthreads();
  }
  float m = red[0];
  __syncthreads();
  float e = valid ? __expf(lv - m) : 0.f;
  red[n] = e;
  __syncthreads();
  for (int off = 64; off > 0; off >>= 1) {
    if (n < off) red[n] += red[n + off];
    __syncthreads();
  }
  float s = red[0];
  if (valid) out[(size_t)b * N + n] = e / s;
}

// ---------------------------------------------------------------------------
// Launch. Chunked over B (Bc as large as the workspace allows). Buffers (bf16
// interleaved [Bc][N][T][C]): Zb1(4) + H1b(4) + Zb2a(8) + H2b(8) + Zb2b(8)
// = 32 NT-floats per b. R15: xp (proj(x) bf16, 2 NT-floats) ALIASES Zb2b —
// xp's lifetime [d12a, cd2<8>] and Zb2b's [cd2<16>, cy] are disjoint within
// an iteration (serial stream), so no extra workspace is needed.
// ---------------------------------------------------------------------------
extern "C" void kernel_launch(void* const* d_in, const int* in_sizes, int n_in,
                              void* d_out, int out_size, void* d_ws, size_t ws_size,
                              hipStream_t stream) {
  const float* x    = (const float*)d_in[0];
  const float* pw   = (const float*)d_in[1];
  const float* pb   = (const float*)d_in[2];
  const float* w_ih = (const float*)d_in[3];
  const float* w_hh = (const float*)d_in[4];
  const float* b_ih = (const float*)d_in[5];
  const float* b_hh = (const float*)d_in[6];
  const float* t1d1 = (const float*)d_in[7];
  const float* t1d2 = (const float*)d_in[8];
  const float* t1c  = (const float*)d_in[9];
  const float* t1r  = (const float*)d_in[10];
  const float* t2d1 = (const float*)d_in[11];
  const float* t2d2 = (const float*)d_in[12];
  const float* t2c  = (const float*)d_in[13];
  const float* t2r  = (const float*)d_in[14];
  const float* t3d1 = (const float*)d_in[15];
  const float* t3d2 = (const float*)d_in[16];
  const float* t3c  = (const float*)d_in[17];
  const float* w4   = (const float*)d_in[18];
  const float* ow   = (const float*)d_in[19];
  const float* ob   = (const float*)d_in[20];
  float* outp = (float*)d_out;

  const size_t NT = (size_t)N * T;            // 12928
  const size_t Bn16 = (size_t)B * N * 16;
  const size_t unit = 32 * NT;                // floats per chunked b
  const size_t fixed = 2 * Bn16 + 8192;       // hl + h4 + apk

  int Bc = 4;
  const int cands[7] = {256, 128, 64, 32, 16, 8, 4};
  for (int i = 0; i < 7; i++) {
    if ((cands[i] * unit + fixed) * sizeof(float) <= ws_size) { Bc = cands[i]; break; }
  }

  float* ws = (float*)d_ws;
  float* hl = ws;                              // [B*N][16]
  float* h4 = hl + Bn16;                       // [B][16][N]
  unsigned short* apk = (unsigned short*)(h4 + Bn16);  // 22*512 ushorts
  float* p = h4 + Bn16 + 8192;
  unsigned short* Zb1  = (unsigned short*)p; p += (size_t)Bc * 4 * NT;
  unsigned short* H1b  = (unsigned short*)p; p += (size_t)Bc * 4 * NT;
  unsigned short* Zb2a = (unsigned short*)p; p += (size_t)Bc * 8 * NT;
  unsigned short* H2b  = (unsigned short*)p; p += (size_t)Bc * 8 * NT;
  unsigned short* Zb2b = (unsigned short*)p;
  unsigned short* Xpb  = Zb2b;  // alias: disjoint lifetimes within iteration

  prep_kernel<<<1, 64, 0, stream>>>(t1c, t2c, t3c, t2d1, t2d2, t3d1, t3d2, apk);
  lstm_kernel<<<(B * N) / 16, 64, 0, stream>>>(x, pw, pb, w_ih, w_hh, b_ih,
                                               b_hh, hl);

  dim3 g(N, Bc);
  dim3 g2(N, Bc / 2);
  for (int b0 = 0; b0 < B; b0 += Bc) {
    d12a_kernel<<<g, 128, 0, stream>>>(x, pw, pb, t1d1, t1d2, Zb1, Xpb, b0);
    cd2_kernel<8, 2><<<g2, 128, 0, stream>>>(
        Zb1, apk + 0 * 512, apk + 15 * 512, Xpb, t1r, H1b, Zb2a, b0);
    cd2_kernel<16, 4><<<g2, 128, 0, stream>>>(
        Zb2a, apk + 3 * 512, apk + 18 * 512, H1b, t2r, H2b, Zb2b, b0);
    cy_kernel<<<g2, 128, 0, stream>>>(Zb2b, apk + 9 * 512, H2b, w4, h4, b0);
  }

  final_kernel<<<B, 128, 0, stream>>>(hl, h4, ow, ob, outp);
}